// Round 4
// baseline (140.758 us; speedup 1.0000x reference)
//
#include <hip/hip_runtime.h>

#define NB 32
#define N0 20000
#define N1 10000
#define N2 10000
#define NP 40000           // N0+N1+N2
#define NK 64
#define TILES 625          // NP / 64
#define CHUNKS 8           // blocks along tile dim per (b, side, cchunk)
#define KC 16              // centers per chunk (4 chunks of 16)

// 64-entry piecewise-linear table over n in [0, ~2.003], one entry per lane.
// SCALE maps n -> "byte" units (4 bytes per entry) so cvt output feeds
// ds_bpermute directly (crossbar ignores the low 2 bits). n < 2 strictly
// (points/centers in [0,1)), so index < 255.6 -> lane <= 63, no wrap.
#define SCALE 127.8f

__global__ __launch_bounds__(256) void hat_kernel(
    const float* __restrict__ up0, const float* __restrict__ down0,
    const float* __restrict__ ext0, const float* __restrict__ ext1,
    const float* __restrict__ centers, const float* __restrict__ radius,
    float* __restrict__ out)
{
    const int lane  = threadIdx.x & 63;
    const int wave  = threadIdx.x >> 6;
    const int b     = blockIdx.y;
    const int side  = blockIdx.z >> 2;    // 0 = up, 1 = down
    const int cc    = blockIdx.z & 3;     // center chunk
    const int cbase = cc * KC;

    const float r = fabsf(radius[0]);

    // ---- in-register table: lane l holds A'[l], B[l] (no LDS) ----
    // g(x) = 1/(1+x) - 1/(1+|r-x|); linear interp in byte units t:
    // val = A'[i] + t*B[i], A' = g0 - (4i)*B, B = (g1-g0)/4.
    float tA, tB;
    {
        const float cell = 4.0f / SCALE;
        const float x0 = lane * cell, x1 = x0 + cell;
        const float g0 = 1.0f/(1.0f+x0) - 1.0f/(1.0f + fabsf(r - x0));
        const float g1 = 1.0f/(1.0f+x1) - 1.0f/(1.0f + fabsf(r - x1));
        tB = (g1 - g0) * 0.25f;
        tA = g0 - (4.0f * lane) * tB;
    }

    // centers for this chunk, rotated (L1 -> Linf) and pre-scaled: SGPRs
    float uc[KC], vc[KC];
    #pragma unroll
    for (int k = 0; k < KC; ++k) {
        const float cx = centers[2*(cbase+k)];
        const float cy = centers[2*(cbase+k)+1];
        uc[k] = (cx + cy) * SCALE;
        vc[k] = (cx - cy) * SCALE;
    }

    const float2* base0 = (const float2*)((side == 0 ? up0 : down0) + (size_t)b * (N0*2));
    const float2* e0    = (const float2*)(ext0 + (size_t)b * (N1*2));
    const float2* e1    = (const float2*)(ext1 + (size_t)b * (N2*2));

    float acc[KC];
    #pragma unroll
    for (int k = 0; k < KC; ++k) acc[k] = 0.f;

    const int iA = __float_as_int(tA);
    const int iB = __float_as_int(tB);

    for (int t = blockIdx.x*4 + wave; t < TILES; t += CHUNKS*4) {
        const int p = t*64 + lane;   // this lane's point
        float px, py;
        if (p < N0) {
            float2 v = base0[p];
            px = v.x; py = v.y;
        } else if (p < N0 + N1) {
            float2 v = e0[p - N0];
            float vv = (side == 0) ? v.y : v.x;   // up uses y, down uses x
            px = vv; py = 1.0f - vv;
        } else {
            float2 v = e1[p - (N0 + N1)];
            float vv = (side == 0) ? v.y : v.x;
            px = vv; py = 1.0f - vv;
        }
        const float up_ = (px + py) * SCALE;   // rotated, pre-scaled
        const float vp_ = (px - py) * SCALE;

        #pragma unroll
        for (int k = 0; k < KC; ++k) {
            const float du = up_ - uc[k];
            const float dv = vp_ - vc[k];
            // |dx|+|dy| == max(|du|,|dv|) (rotation identity), in byte units
            const float tt = fmaxf(fabsf(du), fabsf(dv));
            const int   iv = (int)tt;                       // v_cvt, low 2 bits ignored by crossbar
            const int pa = __builtin_amdgcn_ds_bpermute(iv, iA);
            const int pb = __builtin_amdgcn_ds_bpermute(iv, iB);
            acc[k] += __int_as_float(pa);
            acc[k]  = fmaf(tt, __int_as_float(pb), acc[k]);
        }
    }

    // multi-accumulator butterfly: ends with center (lane>>2)&15 in acc[0]
    {
        #pragma unroll
        for (int k = 0; k < 8; ++k) {
            const bool hi = lane & 32;
            const float send = hi ? acc[k]   : acc[k+8];
            const float keep = hi ? acc[k+8] : acc[k];
            acc[k] = keep + __shfl_xor(send, 32, 64);
        }
        #pragma unroll
        for (int k = 0; k < 4; ++k) {
            const bool hi = lane & 16;
            const float send = hi ? acc[k]   : acc[k+4];
            const float keep = hi ? acc[k+4] : acc[k];
            acc[k] = keep + __shfl_xor(send, 16, 64);
        }
        #pragma unroll
        for (int k = 0; k < 2; ++k) {
            const bool hi = lane & 8;
            const float send = hi ? acc[k]   : acc[k+2];
            const float keep = hi ? acc[k+2] : acc[k];
            acc[k] = keep + __shfl_xor(send, 8, 64);
        }
        {
            const bool hi = lane & 4;
            const float send = hi ? acc[0] : acc[1];
            const float keep = hi ? acc[1] : acc[0];
            acc[0] = keep + __shfl_xor(send, 4, 64);
        }
        acc[0] += __shfl_xor(acc[0], 2, 64);
        acc[0] += __shfl_xor(acc[0], 1, 64);
    }
    if ((lane & 3) == 0) {
        atomicAdd(&out[b*128 + side*64 + cbase + (lane >> 2)], acc[0]);
    }
}

__global__ __launch_bounds__(256) void tpl_kernel(float* __restrict__ out)
{
    __shared__ float red[256];
    float s = 0.f;
    for (int i = threadIdx.x; i < NB*NK; i += 256) {
        const int b = i >> 6, k = i & 63;
        const float d = out[b*128 + k] - out[b*128 + 64 + k];
        s = fmaf(d, d, s);
    }
    red[threadIdx.x] = s;
    __syncthreads();
    for (int w = 128; w > 0; w >>= 1) {
        if (threadIdx.x < w) red[threadIdx.x] += red[threadIdx.x + w];
        __syncthreads();
    }
    if (threadIdx.x == 0) out[NB*2*NK] = -red[0];
}

extern "C" void kernel_launch(void* const* d_in, const int* in_sizes, int n_in,
                              void* d_out, int out_size, void* d_ws, size_t ws_size,
                              hipStream_t stream) {
    const float* up0     = (const float*)d_in[0];
    const float* down0   = (const float*)d_in[1];
    const float* ext0    = (const float*)d_in[2];
    const float* ext1    = (const float*)d_in[3];
    const float* centers = (const float*)d_in[4];
    const float* radius  = (const float*)d_in[5];
    float* out = (float*)d_out;

    // accumulator region must start at zero (harness poisons d_out with 0xAA)
    hipMemsetAsync(out, 0, NB * 2 * NK * sizeof(float), stream);

    dim3 grid(CHUNKS, NB, 8);   // z = side*4 + center-chunk
    hat_kernel<<<grid, 256, 0, stream>>>(up0, down0, ext0, ext1, centers, radius, out);
    tpl_kernel<<<1, 256, 0, stream>>>(out);
}

// Round 6
// 117.767 us; speedup vs baseline: 1.1952x; 1.1952x over previous
//
#include <hip/hip_runtime.h>

#define NB 32
#define N0 20000
#define N1 10000
#define N2 10000
#define TILES 625          // 40000 / 64 points per (b, side)
#define KC 16              // centers per block
#define NWAVES 16          // 1024 threads
#define TBL_N 256
#define TBL_REP 16         // one replica per 4-lane group; entry stride 128 B
#define TBL_DOMAIN 2.05f
#define SCALE_B ((float)(128 * TBL_N) / TBL_DOMAIN)   // n -> byte units

// 256 blocks x 1024 threads: block (b, side, cc) exclusively owns
// out[b*128 + side*64 + cc*16 .. +16) -> no atomics, no memset.
__global__ __launch_bounds__(1024, 4) void hat_kernel(
    const float* __restrict__ up0, const float* __restrict__ down0,
    const float* __restrict__ ext0, const float* __restrict__ ext1,
    const float* __restrict__ centers, const float* __restrict__ radius,
    float* __restrict__ out)
{
    const int tid  = threadIdx.x;
    const int lane = tid & 63;
    const int wave = tid >> 6;
    const int bid  = blockIdx.x;
    const int b    = bid >> 3;
    const int side = (bid >> 2) & 1;
    const int cc   = bid & 3;
    const int cbase = cc * KC;

    __shared__ float2 tab[TBL_N * TBL_REP];   // 32 KB
    __shared__ float  red[NWAVES * KC];       // 1 KB

    const float r = fabsf(radius[0]);
    const float S = SCALE_B;

    // ---- f32 table (R3-validated math): val = A[i] + tt*B[i], tt byte-scaled.
    // Replica c (= lane>>2) at byte i*128 + c*8 -> dword banks {2c, 2c+1}:
    // every wave b64 read = uniform 4 accesses/bank (the structural floor).
    if (tid < TBL_N) {
        const float h  = TBL_DOMAIN / (float)TBL_N;
        const float x0 = tid * h, x1 = x0 + h;
        const float g0 = 1.0f/(1.0f+x0) - 1.0f/(1.0f + fabsf(r - x0));
        const float g1 = 1.0f/(1.0f+x1) - 1.0f/(1.0f + fabsf(r - x1));
        const float dT = g1 - g0;
        float2 v;
        v.x = g0 - (float)tid * dT;      // A anchored at t=0
        v.y = dT * (1.0f/128.0f);        // B per byte unit
        #pragma unroll
        for (int c = 0; c < TBL_REP; ++c) tab[tid * TBL_REP + c] = v;
    }
    __syncthreads();

    // centers, rotated (L1 -> Linf) and byte-scaled: wave-uniform -> SGPRs
    float uc[KC], vc[KC];
    #pragma unroll
    for (int k = 0; k < KC; ++k) {
        const float cx = centers[2*(cbase+k)];
        const float cy = centers[2*(cbase+k)+1];
        uc[k] = (cx + cy) * S;
        vc[k] = (cx - cy) * S;
    }
    const float r_b = r * S;   // radius in byte units (exact path works scaled)

    const float2* base0 = (const float2*)((side == 0 ? up0 : down0) + (size_t)b * (N0*2));
    const float2* e0    = (const float2*)(ext0 + (size_t)b * (N1*2));
    const float2* e1    = (const float2*)(ext1 + (size_t)b * (N2*2));

    const int laneoff = (lane & 60) << 1;     // (lane>>2)*8 byte replica offset
    const char* tbase = (const char*)tab;

    float acc[KC];
    #pragma unroll
    for (int k = 0; k < KC; ++k) acc[k] = 0.f;

    for (int t = wave; t < TILES; t += NWAVES) {
        const int p = t*64 + lane;
        float px, py;
        if (p < N0) {
            float2 v = base0[p];
            px = v.x; py = v.y;
        } else if (p < N0 + N1) {
            float2 v = e0[p - N0];
            float vv = (side == 0) ? v.y : v.x;   // up uses y, down uses x
            px = vv; py = 1.0f - vv;
        } else {
            float2 v = e1[p - (N0 + N1)];
            float vv = (side == 0) ? v.y : v.x;
            px = vv; py = 1.0f - vv;
        }
        const float u_ = (px + py) * S;   // rotated, byte-scaled
        const float v_ = (px - py) * S;

        #pragma unroll
        for (int k = 0; k < KC; ++k) {
            const float du = u_ - uc[k];
            const float dv = v_ - vc[k];
            const float tt = fmaxf(fabsf(du), fabsf(dv));  // L1 dist, byte units
            if ((k & 3) == 3) {
                // exact path (R2-validated), in byte units; *S deferred to end:
                // g = S*(|r-n| - n) / ((S+n)(S+|r-n|))
                const float rn = r_b - tt;
                const float d1 = S + tt;
                const float d2 = S + fabsf(rn);
                const float rc = __builtin_amdgcn_rcpf(d1 * d2);
                acc[k] = fmaf(fabsf(rn) - tt, rc, acc[k]);
            } else {
                const int   iv   = (int)tt;
                const int   addr = (iv & ~127) | laneoff;
                const float2 ab  = *(const float2*)(tbase + addr);  // ds_read_b64
                acc[k] += ab.x;
                acc[k]  = fmaf(tt, ab.y, acc[k]);
            }
        }
    }
    #pragma unroll
    for (int k = 0; k < KC; ++k) if ((k & 3) == 3) acc[k] *= S;  // deferred scale

    // validated KC=16 butterfly: ends with center (lane>>2)&15 in acc[0]
    {
        #pragma unroll
        for (int k = 0; k < 8; ++k) {
            const bool hi = lane & 32;
            const float send = hi ? acc[k]   : acc[k+8];
            const float keep = hi ? acc[k+8] : acc[k];
            acc[k] = keep + __shfl_xor(send, 32, 64);
        }
        #pragma unroll
        for (int k = 0; k < 4; ++k) {
            const bool hi = lane & 16;
            const float send = hi ? acc[k]   : acc[k+4];
            const float keep = hi ? acc[k+4] : acc[k];
            acc[k] = keep + __shfl_xor(send, 16, 64);
        }
        #pragma unroll
        for (int k = 0; k < 2; ++k) {
            const bool hi = lane & 8;
            const float send = hi ? acc[k]   : acc[k+2];
            const float keep = hi ? acc[k+2] : acc[k];
            acc[k] = keep + __shfl_xor(send, 8, 64);
        }
        {
            const bool hi = lane & 4;
            const float send = hi ? acc[0] : acc[1];
            const float keep = hi ? acc[1] : acc[0];
            acc[0] = keep + __shfl_xor(send, 4, 64);
        }
        acc[0] += __shfl_xor(acc[0], 2, 64);
        acc[0] += __shfl_xor(acc[0], 1, 64);
    }
    if ((lane & 3) == 0) red[wave * KC + (lane >> 2)] = acc[0];
    __syncthreads();
    if (tid < KC) {
        float s = 0.f;
        #pragma unroll
        for (int w = 0; w < NWAVES; ++w) s += red[w * KC + tid];
        out[b*128 + side*64 + cbase + tid] = s;   // exclusive direct store
    }
}

__global__ __launch_bounds__(256) void tpl_kernel(float* __restrict__ out)
{
    __shared__ float red[256];
    float s = 0.f;
    for (int i = threadIdx.x; i < NB*64; i += 256) {
        const int b = i >> 6, k = i & 63;
        const float d = out[b*128 + k] - out[b*128 + 64 + k];
        s = fmaf(d, d, s);
    }
    red[threadIdx.x] = s;
    __syncthreads();
    for (int w = 128; w > 0; w >>= 1) {
        if (threadIdx.x < w) red[threadIdx.x] += red[threadIdx.x + w];
        __syncthreads();
    }
    if (threadIdx.x == 0) out[NB*128] = -red[0];
}

extern "C" void kernel_launch(void* const* d_in, const int* in_sizes, int n_in,
                              void* d_out, int out_size, void* d_ws, size_t ws_size,
                              hipStream_t stream) {
    const float* up0     = (const float*)d_in[0];
    const float* down0   = (const float*)d_in[1];
    const float* ext0    = (const float*)d_in[2];
    const float* ext1    = (const float*)d_in[3];
    const float* centers = (const float*)d_in[4];
    const float* radius  = (const float*)d_in[5];
    float* out = (float*)d_out;

    hat_kernel<<<dim3(NB * 8), dim3(1024), 0, stream>>>(
        up0, down0, ext0, ext1, centers, radius, out);
    tpl_kernel<<<1, 256, 0, stream>>>(out);
}